// Round 1
// baseline (733.962 us; speedup 1.0000x reference)
//
#include <hip/hip_runtime.h>
#include <hip/hip_bf16.h>
#include <stdint.h>

#define N_NODES 100000
#define IN_CH   128
#define HID     128
#define OUT_CH  64
#define N_EDGES 1600000
#define SCAN_TILE 1024
#define N_TILES   ((N_NODES + SCAN_TILE - 1) / SCAN_TILE)   // 98

// ---------------- CSR build ----------------

__global__ __launch_bounds__(256) void k_count(const int* __restrict__ dst,
                                               int* __restrict__ cnt) {
    int e = blockIdx.x * 256 + threadIdx.x;
    if (e < N_EDGES) atomicAdd(&cnt[dst[e]], 1);
}

__global__ __launch_bounds__(256) void k_dinv(const int* __restrict__ cnt,
                                              float* __restrict__ dinv) {
    int i = blockIdx.x * 256 + threadIdx.x;
    if (i < N_NODES) dinv[i] = rsqrtf((float)cnt[i] + 1.0f);  // +1 self loop
}

// per-tile exclusive scan of cnt -> rowptr (local), tile sums out
__global__ __launch_bounds__(256) void k_scanA(const int* __restrict__ cnt,
                                               int* __restrict__ rowptr,
                                               int* __restrict__ tileSum) {
    __shared__ int sdata[256];
    int b = blockIdx.x, t = threadIdx.x;
    int idx = b * SCAN_TILE + t * 4;
    int v[4];
#pragma unroll
    for (int j = 0; j < 4; j++) v[j] = (idx + j < N_NODES) ? cnt[idx + j] : 0;
    int s = v[0] + v[1] + v[2] + v[3];
    sdata[t] = s;
    __syncthreads();
    int val = s;
    for (int off = 1; off < 256; off <<= 1) {
        int tmp = (t >= off) ? sdata[t - off] : 0;
        __syncthreads();
        val += tmp;
        sdata[t] = val;
        __syncthreads();
    }
    int p = val - s;  // exclusive prefix of thread sums
    int e0 = p, e1 = p + v[0], e2 = e1 + v[1], e3 = e2 + v[2];
    if (idx + 0 < N_NODES) rowptr[idx + 0] = e0;
    if (idx + 1 < N_NODES) rowptr[idx + 1] = e1;
    if (idx + 2 < N_NODES) rowptr[idx + 2] = e2;
    if (idx + 3 < N_NODES) rowptr[idx + 3] = e3;
    if (t == 255) tileSum[b] = val;
}

__global__ __launch_bounds__(128) void k_scanB(const int* __restrict__ tileSum,
                                               int* __restrict__ tileOff,
                                               int* __restrict__ rowptr) {
    __shared__ int sdata[128];
    int t = threadIdx.x;
    int s = (t < N_TILES) ? tileSum[t] : 0;
    sdata[t] = s;
    __syncthreads();
    int val = s;
    for (int off = 1; off < 128; off <<= 1) {
        int tmp = (t >= off) ? sdata[t - off] : 0;
        __syncthreads();
        val += tmp;
        sdata[t] = val;
        __syncthreads();
    }
    tileOff[t] = val - s;
    if (t == 127) rowptr[N_NODES] = val;  // == N_EDGES
}

__global__ __launch_bounds__(256) void k_scanC(int* __restrict__ rowptr,
                                               const int* __restrict__ tileOff) {
    int i = blockIdx.x * 256 + threadIdx.x;
    if (i < N_NODES) rowptr[i] += tileOff[i >> 10];
}

__global__ __launch_bounds__(256) void k_fill(const int* __restrict__ src,
                                              const int* __restrict__ dst,
                                              const int* __restrict__ rowptr,
                                              int* __restrict__ fill,
                                              const float* __restrict__ dinv,
                                              int* __restrict__ csr_src,
                                              float* __restrict__ csr_norm) {
    int e = blockIdx.x * 256 + threadIdx.x;
    if (e < N_EDGES) {
        int s = src[e], d = dst[e];
        int pos = rowptr[d] + atomicAdd(&fill[d], 1);
        csr_src[pos] = s;
        csr_norm[pos] = dinv[s] * dinv[d];
    }
}

// ---------------- dense GEMM (f32, K=128 fixed) ----------------

__global__ __launch_bounds__(256) void k_pack(const float* __restrict__ Wmu,
                                              const float* __restrict__ Wls,
                                              float* __restrict__ Wcat) {
    int idx = blockIdx.x * 256 + threadIdx.x;
    if (idx < 128 * 128) {
        int k = idx >> 7, c = idx & 127;
        Wcat[idx] = (c < 64) ? Wmu[k * 64 + c] : Wls[k * 64 + (c - 64)];
    }
}

#define GROWS 32
__global__ __launch_bounds__(256) void k_gemm(const float* __restrict__ X,
                                              const float* __restrict__ W,
                                              float* __restrict__ Y) {
    __shared__ float sW[128 * 128];   // 64 KiB
    __shared__ float sX[GROWS * 128]; // 16 KiB
    int t = threadIdx.x;
    {
        const float4* W4 = (const float4*)W;
        float4* sW4 = (float4*)sW;
#pragma unroll
        for (int j = 0; j < 16; j++) sW4[t + 256 * j] = W4[t + 256 * j];
        const float4* X4 = (const float4*)(X + (size_t)blockIdx.x * GROWS * 128);
        float4* sX4 = (float4*)sX;
#pragma unroll
        for (int j = 0; j < 4; j++) sX4[t + 256 * j] = X4[t + 256 * j];
    }
    __syncthreads();

    int tx = t & 31;   // 32 col-groups of 4
    int ty = t >> 5;   // 8 row-groups of 4
    float acc[4][4] = {};

#pragma unroll 2
    for (int k0 = 0; k0 < 128; k0 += 4) {
        float4 xq[4];
#pragma unroll
        for (int r = 0; r < 4; r++)
            xq[r] = *(const float4*)&sX[(ty * 4 + r) * 128 + k0];
#pragma unroll
        for (int kk = 0; kk < 4; kk++) {
            float4 w = *(const float4*)&sW[(k0 + kk) * 128 + tx * 4];
#pragma unroll
            for (int r = 0; r < 4; r++) {
                float xv = ((const float*)&xq[r])[kk];
                acc[r][0] = fmaf(xv, w.x, acc[r][0]);
                acc[r][1] = fmaf(xv, w.y, acc[r][1]);
                acc[r][2] = fmaf(xv, w.z, acc[r][2]);
                acc[r][3] = fmaf(xv, w.w, acc[r][3]);
            }
        }
    }
    float* Yb = Y + (size_t)blockIdx.x * GROWS * 128;
#pragma unroll
    for (int r = 0; r < 4; r++)
        *(float4*)&Yb[(ty * 4 + r) * 128 + tx * 4] =
            make_float4(acc[r][0], acc[r][1], acc[r][2], acc[r][3]);
}

// ---------------- aggregations (CSR gather, one block per node) ----------------

__global__ __launch_bounds__(128) void k_agg1(const float* __restrict__ h0,
                                              const int* __restrict__ rowptr,
                                              const int* __restrict__ csr_src,
                                              const float* __restrict__ csr_norm,
                                              const float* __restrict__ dinv,
                                              const float* __restrict__ b1,
                                              float* __restrict__ h) {
    int i = blockIdx.x;
    int c = threadIdx.x;
    float di = dinv[i];
    float acc = h0[(size_t)i * 128 + c] * (di * di);
    int beg = rowptr[i], end = rowptr[i + 1];
    for (int p = beg; p < end; ++p) {
        int s = csr_src[p];
        float nm = csr_norm[p];
        acc = fmaf(h0[(size_t)s * 128 + c], nm, acc);
    }
    float r = acc + b1[c];
    h[(size_t)i * 128 + c] = r > 0.f ? r : 0.f;
}

__global__ __launch_bounds__(128) void k_agg2(const float* __restrict__ tt,
                                              const int* __restrict__ rowptr,
                                              const int* __restrict__ csr_src,
                                              const float* __restrict__ csr_norm,
                                              const float* __restrict__ dinv,
                                              const float* __restrict__ bmu,
                                              const float* __restrict__ bls,
                                              float* __restrict__ out) {
    int i = blockIdx.x;
    int c = threadIdx.x;
    float di = dinv[i];
    float acc = tt[(size_t)i * 128 + c] * (di * di);
    int beg = rowptr[i], end = rowptr[i + 1];
    for (int p = beg; p < end; ++p) {
        acc = fmaf(tt[(size_t)csr_src[p] * 128 + c], csr_norm[p], acc);
    }
    if (c < 64)
        out[(size_t)i * 64 + c] = acc + bmu[c];
    else
        out[(size_t)N_NODES * 64 + (size_t)i * 64 + (c - 64)] = acc + bls[c - 64];
}

// ---------------- launch ----------------

extern "C" void kernel_launch(void* const* d_in, const int* in_sizes, int n_in,
                              void* d_out, int out_size, void* d_ws, size_t ws_size,
                              hipStream_t stream) {
    const float* x    = (const float*)d_in[0];
    const int*   ei   = (const int*)d_in[1];
    const float* W1   = (const float*)d_in[2];
    const float* b1   = (const float*)d_in[3];
    const float* Wmu  = (const float*)d_in[4];
    const float* bmu  = (const float*)d_in[5];
    const float* Wls  = (const float*)d_in[6];
    const float* bls  = (const float*)d_in[7];
    const int* src = ei;
    const int* dst = ei + N_EDGES;

    char* p = (char*)d_ws;
    float* bufA    = (float*)p; p += (size_t)N_NODES * 128 * 4;   // 51.2 MB: h0, then t
    float* bufB    = (float*)p; p += (size_t)N_NODES * 128 * 4;   // 51.2 MB: h
    float* Wcat    = (float*)p; p += 128 * 128 * 4;               // 64 KiB
    int*   cnt     = (int*)p;   p += 400000;
    int*   fill    = (int*)p;   p += 400000;
    int*   rowptr  = (int*)p;   p += 400016;                      // 100001 ints, padded
    float* dinv    = (float*)p; p += 400000;
    int*   tileSum = (int*)p;   p += 512;
    int*   tileOff = (int*)p;   p += 512;
    int*   csr_src = (int*)p;   p += (size_t)N_EDGES * 4;
    float* csr_nrm = (float*)p; p += (size_t)N_EDGES * 4;

    hipMemsetAsync(cnt, 0, N_NODES * sizeof(int), stream);
    hipMemsetAsync(fill, 0, N_NODES * sizeof(int), stream);

    int eb = (N_EDGES + 255) / 256;   // 6250
    int nb = (N_NODES + 255) / 256;   // 391

    k_count<<<eb, 256, 0, stream>>>(dst, cnt);
    k_dinv<<<nb, 256, 0, stream>>>(cnt, dinv);
    k_scanA<<<N_TILES, 256, 0, stream>>>(cnt, rowptr, tileSum);
    k_scanB<<<1, 128, 0, stream>>>(tileSum, tileOff, rowptr);
    k_scanC<<<nb, 256, 0, stream>>>(rowptr, tileOff);
    k_fill<<<eb, 256, 0, stream>>>(src, dst, rowptr, fill, dinv, csr_src, csr_nrm);

    k_pack<<<64, 256, 0, stream>>>(Wmu, Wls, Wcat);

    // layer 1: h0 = x @ W1 ; h = relu(agg(h0) + b1)
    k_gemm<<<N_NODES / GROWS, 256, 0, stream>>>(x, W1, bufA);
    k_agg1<<<N_NODES, 128, 0, stream>>>(bufA, rowptr, csr_src, csr_nrm, dinv, b1, bufB);

    // layer 2: t = h @ [Wmu|Wls] ; out = agg(t) + bias
    k_gemm<<<N_NODES / GROWS, 256, 0, stream>>>(bufB, Wcat, bufA);
    k_agg2<<<N_NODES, 128, 0, stream>>>(bufA, rowptr, csr_src, csr_nrm, dinv,
                                        bmu, bls, (float*)d_out);
}

// Round 2
// 481.535 us; speedup vs baseline: 1.5242x; 1.5242x over previous
//
#include <hip/hip_runtime.h>
#include <hip/hip_bf16.h>
#include <stdint.h>

#define N_NODES 100000
#define IN_CH   128
#define HID     128
#define OUT_CH  64
#define N_EDGES 1600000
#define SCAN_TILE 1024
#define N_TILES   ((N_NODES + SCAN_TILE - 1) / SCAN_TILE)   // 98

// ---------------- helpers ----------------

__device__ __forceinline__ unsigned short f2bf(float f) {   // RNE f32->bf16
    unsigned int u = __float_as_uint(f);
    u = (u + 0x7fffu + ((u >> 16) & 1u)) >> 16;
    return (unsigned short)u;
}
__device__ __forceinline__ float bfl(unsigned int u) {      // low bf16 of pair
    return __uint_as_float(u << 16);
}
__device__ __forceinline__ float bfh(unsigned int u) {      // high bf16 of pair
    return __uint_as_float(u & 0xffff0000u);
}

// ---------------- CSR build ----------------

__global__ __launch_bounds__(256) void k_count(const int* __restrict__ dst,
                                               int* __restrict__ cnt) {
    int e = blockIdx.x * 256 + threadIdx.x;
    if (e < N_EDGES) atomicAdd(&cnt[dst[e]], 1);
}

__global__ __launch_bounds__(256) void k_dinv(const int* __restrict__ cnt,
                                              float* __restrict__ dinv) {
    int i = blockIdx.x * 256 + threadIdx.x;
    if (i < N_NODES) dinv[i] = rsqrtf((float)cnt[i] + 1.0f);  // +1 self loop
}

__global__ __launch_bounds__(256) void k_scanA(const int* __restrict__ cnt,
                                               int* __restrict__ rowptr,
                                               int* __restrict__ tileSum) {
    __shared__ int sdata[256];
    int b = blockIdx.x, t = threadIdx.x;
    int idx = b * SCAN_TILE + t * 4;
    int v[4];
#pragma unroll
    for (int j = 0; j < 4; j++) v[j] = (idx + j < N_NODES) ? cnt[idx + j] : 0;
    int s = v[0] + v[1] + v[2] + v[3];
    sdata[t] = s;
    __syncthreads();
    int val = s;
    for (int off = 1; off < 256; off <<= 1) {
        int tmp = (t >= off) ? sdata[t - off] : 0;
        __syncthreads();
        val += tmp;
        sdata[t] = val;
        __syncthreads();
    }
    int p = val - s;
    int e0 = p, e1 = p + v[0], e2 = e1 + v[1], e3 = e2 + v[2];
    if (idx + 0 < N_NODES) rowptr[idx + 0] = e0;
    if (idx + 1 < N_NODES) rowptr[idx + 1] = e1;
    if (idx + 2 < N_NODES) rowptr[idx + 2] = e2;
    if (idx + 3 < N_NODES) rowptr[idx + 3] = e3;
    if (t == 255) tileSum[b] = val;
}

__global__ __launch_bounds__(128) void k_scanB(const int* __restrict__ tileSum,
                                               int* __restrict__ tileOff,
                                               int* __restrict__ rowptr) {
    __shared__ int sdata[128];
    int t = threadIdx.x;
    int s = (t < N_TILES) ? tileSum[t] : 0;
    sdata[t] = s;
    __syncthreads();
    int val = s;
    for (int off = 1; off < 128; off <<= 1) {
        int tmp = (t >= off) ? sdata[t - off] : 0;
        __syncthreads();
        val += tmp;
        sdata[t] = val;
        __syncthreads();
    }
    tileOff[t] = val - s;
    if (t == 127) rowptr[N_NODES] = val;
}

__global__ __launch_bounds__(256) void k_scanC(int* __restrict__ rowptr,
                                               const int* __restrict__ tileOff) {
    int i = blockIdx.x * 256 + threadIdx.x;
    if (i < N_NODES) rowptr[i] += tileOff[i >> 10];
}

__global__ __launch_bounds__(256) void k_fill(const int* __restrict__ src,
                                              const int* __restrict__ dst,
                                              const int* __restrict__ rowptr,
                                              int* __restrict__ fill,
                                              const float* __restrict__ dinv,
                                              int2* __restrict__ csr) {
    int e = blockIdx.x * 256 + threadIdx.x;
    if (e < N_EDGES) {
        int s = src[e], d = dst[e];
        int pos = rowptr[d] + atomicAdd(&fill[d], 1);
        int2 v;
        v.x = s;
        v.y = __float_as_int(dinv[s] * dinv[d]);
        csr[pos] = v;
    }
}

// ---------------- dense GEMM (f32 in, bf16 out, K=128 fixed) ----------------

__global__ __launch_bounds__(256) void k_pack(const float* __restrict__ Wmu,
                                              const float* __restrict__ Wls,
                                              float* __restrict__ Wcat) {
    int idx = blockIdx.x * 256 + threadIdx.x;
    if (idx < 128 * 128) {
        int k = idx >> 7, c = idx & 127;
        Wcat[idx] = (c < 64) ? Wmu[k * 64 + c] : Wls[k * 64 + (c - 64)];
    }
}

#define GROWS 32
__global__ __launch_bounds__(256) void k_gemm(const float* __restrict__ X,
                                              const float* __restrict__ W,
                                              unsigned short* __restrict__ Y) {
    __shared__ float sW[128 * 128];   // 64 KiB
    __shared__ float sX[GROWS * 128]; // 16 KiB
    int t = threadIdx.x;
    {
        const float4* W4 = (const float4*)W;
        float4* sW4 = (float4*)sW;
#pragma unroll
        for (int j = 0; j < 16; j++) sW4[t + 256 * j] = W4[t + 256 * j];
        const float4* X4 = (const float4*)(X + (size_t)blockIdx.x * GROWS * 128);
        float4* sX4 = (float4*)sX;
#pragma unroll
        for (int j = 0; j < 4; j++) sX4[t + 256 * j] = X4[t + 256 * j];
    }
    __syncthreads();

    int tx = t & 31;
    int ty = t >> 5;
    float acc[4][4] = {};

#pragma unroll 2
    for (int k0 = 0; k0 < 128; k0 += 4) {
        float4 xq[4];
#pragma unroll
        for (int r = 0; r < 4; r++)
            xq[r] = *(const float4*)&sX[(ty * 4 + r) * 128 + k0];
#pragma unroll
        for (int kk = 0; kk < 4; kk++) {
            float4 w = *(const float4*)&sW[(k0 + kk) * 128 + tx * 4];
#pragma unroll
            for (int r = 0; r < 4; r++) {
                float xv = ((const float*)&xq[r])[kk];
                acc[r][0] = fmaf(xv, w.x, acc[r][0]);
                acc[r][1] = fmaf(xv, w.y, acc[r][1]);
                acc[r][2] = fmaf(xv, w.z, acc[r][2]);
                acc[r][3] = fmaf(xv, w.w, acc[r][3]);
            }
        }
    }
    unsigned short* Yb = Y + (size_t)blockIdx.x * GROWS * 128;
#pragma unroll
    for (int r = 0; r < 4; r++) {
        ushort4 o;
        o.x = f2bf(acc[r][0]);
        o.y = f2bf(acc[r][1]);
        o.z = f2bf(acc[r][2]);
        o.w = f2bf(acc[r][3]);
        *(ushort4*)&Yb[(ty * 4 + r) * 128 + tx * 4] = o;
    }
}

// ---------------- aggregations (CSR gather, one wave per node) ----------------
// bf16 gather operand, f32 accumulate. Lane l handles channels 2l, 2l+1.
// Node index readfirstlane'd so edge metadata goes through the scalar pipe.

__global__ __launch_bounds__(256) void k_agg1(const unsigned short* __restrict__ h0,
                                              const int* __restrict__ rowptr,
                                              const int2* __restrict__ csr,
                                              const float* __restrict__ dinv,
                                              const float* __restrict__ b1,
                                              float* __restrict__ h) {
    int lane = threadIdx.x & 63;
    int i = __builtin_amdgcn_readfirstlane(blockIdx.x * 4 + (threadIdx.x >> 6));
    int c2 = lane * 2;
    float di = dinv[i];
    float nself = di * di;
    unsigned int sv = *(const unsigned int*)(h0 + (size_t)i * 128 + c2);
    float ax = bfl(sv) * nself, ay = bfh(sv) * nself;
    int beg = rowptr[i], end = rowptr[i + 1];
    int p = beg;
    for (; p + 4 <= end; p += 4) {
        int2 e0 = csr[p + 0], e1 = csr[p + 1], e2 = csr[p + 2], e3 = csr[p + 3];
        unsigned int r0 = *(const unsigned int*)(h0 + (size_t)e0.x * 128 + c2);
        unsigned int r1 = *(const unsigned int*)(h0 + (size_t)e1.x * 128 + c2);
        unsigned int r2 = *(const unsigned int*)(h0 + (size_t)e2.x * 128 + c2);
        unsigned int r3 = *(const unsigned int*)(h0 + (size_t)e3.x * 128 + c2);
        float n0 = __int_as_float(e0.y), n1 = __int_as_float(e1.y);
        float n2 = __int_as_float(e2.y), n3 = __int_as_float(e3.y);
        ax = fmaf(bfl(r0), n0, ax); ay = fmaf(bfh(r0), n0, ay);
        ax = fmaf(bfl(r1), n1, ax); ay = fmaf(bfh(r1), n1, ay);
        ax = fmaf(bfl(r2), n2, ax); ay = fmaf(bfh(r2), n2, ay);
        ax = fmaf(bfl(r3), n3, ax); ay = fmaf(bfh(r3), n3, ay);
    }
    for (; p < end; ++p) {
        int2 e = csr[p];
        unsigned int r = *(const unsigned int*)(h0 + (size_t)e.x * 128 + c2);
        float n = __int_as_float(e.y);
        ax = fmaf(bfl(r), n, ax); ay = fmaf(bfh(r), n, ay);
    }
    ax += b1[c2]; ay += b1[c2 + 1];
    ax = ax > 0.f ? ax : 0.f;
    ay = ay > 0.f ? ay : 0.f;
    *(float2*)(h + (size_t)i * 128 + c2) = make_float2(ax, ay);
}

__global__ __launch_bounds__(256) void k_agg2(const unsigned short* __restrict__ tt,
                                              const int* __restrict__ rowptr,
                                              const int2* __restrict__ csr,
                                              const float* __restrict__ dinv,
                                              const float* __restrict__ bmu,
                                              const float* __restrict__ bls,
                                              float* __restrict__ out) {
    int lane = threadIdx.x & 63;
    int i = __builtin_amdgcn_readfirstlane(blockIdx.x * 4 + (threadIdx.x >> 6));
    int c2 = lane * 2;
    float di = dinv[i];
    float nself = di * di;
    unsigned int sv = *(const unsigned int*)(tt + (size_t)i * 128 + c2);
    float ax = bfl(sv) * nself, ay = bfh(sv) * nself;
    int beg = rowptr[i], end = rowptr[i + 1];
    int p = beg;
    for (; p + 4 <= end; p += 4) {
        int2 e0 = csr[p + 0], e1 = csr[p + 1], e2 = csr[p + 2], e3 = csr[p + 3];
        unsigned int r0 = *(const unsigned int*)(tt + (size_t)e0.x * 128 + c2);
        unsigned int r1 = *(const unsigned int*)(tt + (size_t)e1.x * 128 + c2);
        unsigned int r2 = *(const unsigned int*)(tt + (size_t)e2.x * 128 + c2);
        unsigned int r3 = *(const unsigned int*)(tt + (size_t)e3.x * 128 + c2);
        float n0 = __int_as_float(e0.y), n1 = __int_as_float(e1.y);
        float n2 = __int_as_float(e2.y), n3 = __int_as_float(e3.y);
        ax = fmaf(bfl(r0), n0, ax); ay = fmaf(bfh(r0), n0, ay);
        ax = fmaf(bfl(r1), n1, ax); ay = fmaf(bfh(r1), n1, ay);
        ax = fmaf(bfl(r2), n2, ax); ay = fmaf(bfh(r2), n2, ay);
        ax = fmaf(bfl(r3), n3, ax); ay = fmaf(bfh(r3), n3, ay);
    }
    for (; p < end; ++p) {
        int2 e = csr[p];
        unsigned int r = *(const unsigned int*)(tt + (size_t)e.x * 128 + c2);
        float n = __int_as_float(e.y);
        ax = fmaf(bfl(r), n, ax); ay = fmaf(bfh(r), n, ay);
    }
    if (lane < 32) {
        int c = c2;                       // mu channels 0..63
        *(float2*)(out + (size_t)i * 64 + c) =
            make_float2(ax + bmu[c], ay + bmu[c + 1]);
    } else {
        int c = c2 - 64;                  // logstd channels 0..63
        *(float2*)(out + (size_t)N_NODES * 64 + (size_t)i * 64 + c) =
            make_float2(ax + bls[c], ay + bls[c + 1]);
    }
}

// ---------------- launch ----------------

extern "C" void kernel_launch(void* const* d_in, const int* in_sizes, int n_in,
                              void* d_out, int out_size, void* d_ws, size_t ws_size,
                              hipStream_t stream) {
    const float* x    = (const float*)d_in[0];
    const int*   ei   = (const int*)d_in[1];
    const float* W1   = (const float*)d_in[2];
    const float* b1   = (const float*)d_in[3];
    const float* Wmu  = (const float*)d_in[4];
    const float* bmu  = (const float*)d_in[5];
    const float* Wls  = (const float*)d_in[6];
    const float* bls  = (const float*)d_in[7];
    const int* src = ei;
    const int* dst = ei + N_EDGES;

    char* p = (char*)d_ws;
    unsigned short* bufA = (unsigned short*)p; p += (size_t)N_NODES * 128 * 2; // 25.6 MB bf16: h0, then t
    float* bufB    = (float*)p; p += (size_t)N_NODES * 128 * 4;                // 51.2 MB f32: h
    float* Wcat    = (float*)p; p += 128 * 128 * 4;
    int*   cnt     = (int*)p;   p += 400000;
    int*   fill    = (int*)p;   p += 400000;
    int*   rowptr  = (int*)p;   p += 400016;
    float* dinv    = (float*)p; p += 400000;
    int*   tileSum = (int*)p;   p += 512;
    int*   tileOff = (int*)p;   p += 512;
    int2*  csr     = (int2*)p;  p += (size_t)N_EDGES * 8;

    hipMemsetAsync(cnt, 0, N_NODES * sizeof(int), stream);
    hipMemsetAsync(fill, 0, N_NODES * sizeof(int), stream);

    int eb = (N_EDGES + 255) / 256;
    int nb = (N_NODES + 255) / 256;

    k_count<<<eb, 256, 0, stream>>>(dst, cnt);
    k_dinv<<<nb, 256, 0, stream>>>(cnt, dinv);
    k_scanA<<<N_TILES, 256, 0, stream>>>(cnt, rowptr, tileSum);
    k_scanB<<<1, 128, 0, stream>>>(tileSum, tileOff, rowptr);
    k_scanC<<<nb, 256, 0, stream>>>(rowptr, tileOff);
    k_fill<<<eb, 256, 0, stream>>>(src, dst, rowptr, fill, dinv, csr);

    k_pack<<<64, 256, 0, stream>>>(Wmu, Wls, Wcat);

    // layer 1: h0 = x @ W1 (bf16) ; h = relu(agg(h0) + b1) (f32)
    k_gemm<<<N_NODES / GROWS, 256, 0, stream>>>(x, W1, bufA);
    k_agg1<<<N_NODES / 4, 256, 0, stream>>>(bufA, rowptr, csr, dinv, b1, bufB);

    // layer 2: t = h @ [Wmu|Wls] (bf16) ; out = agg(t) + bias (f32)
    k_gemm<<<N_NODES / GROWS, 256, 0, stream>>>(bufB, Wcat, bufA);
    k_agg2<<<N_NODES / 4, 256, 0, stream>>>(bufA, rowptr, csr, dinv,
                                            bmu, bls, (float*)d_out);
}

// Round 3
// 399.281 us; speedup vs baseline: 1.8382x; 1.2060x over previous
//
#include <hip/hip_runtime.h>
#include <hip/hip_bf16.h>
#include <stdint.h>

#define N_NODES 100000
#define IN_CH   128
#define HID     128
#define OUT_CH  64
#define N_EDGES 1600000

#define NB    196      // buckets of 512 nodes: ceil(100000/512)
#define NBLK  250      // edge-partition blocks for phases A/B
#define EPB   6400     // edges per block (250*6400 = 1.6M)

// ---------------- helpers ----------------

__device__ __forceinline__ unsigned short f2bf(float f) {   // RNE f32->bf16
    unsigned int u = __float_as_uint(f);
    u = (u + 0x7fffu + ((u >> 16) & 1u)) >> 16;
    return (unsigned short)u;
}
__device__ __forceinline__ float bfl(unsigned int u) { return __uint_as_float(u << 16); }
__device__ __forceinline__ float bfh(unsigned int u) { return __uint_as_float(u & 0xffff0000u); }

// ---------------- CSR build: bucket sort ----------------

// Phase A: per-(block,bucket) histogram. No global atomics.
__global__ __launch_bounds__(256) void k_phaseA(const int* __restrict__ dst,
                                                int* __restrict__ Cm) {
    __shared__ int hist[NB];
    int blk = blockIdx.x, t = threadIdx.x;
    if (t < NB) hist[t] = 0;
    __syncthreads();
    int base = blk * EPB;
#pragma unroll 5
    for (int k = 0; k < EPB / 256; k++) {
        int d = dst[base + k * 256 + t];
        atomicAdd(&hist[d >> 9], 1);
    }
    __syncthreads();
    if (t < NB) Cm[blk * NB + t] = hist[t];
}

// Scan: Cm[blk][bkt] -> exclusive prefix over blocks (per bucket); bucket bases.
__global__ __launch_bounds__(256) void k_scanCm(int* __restrict__ Cm,
                                                int* __restrict__ bktBase) {
    __shared__ int sdata[256];
    int t = threadIdx.x;
    int run = 0;
    if (t < NB) {
        for (int blk = 0; blk < NBLK; blk++) {
            int idx = blk * NB + t;
            int v = Cm[idx];
            Cm[idx] = run;
            run += v;
        }
    }
    int s = (t < NB) ? run : 0;
    sdata[t] = s;
    __syncthreads();
    int val = s;
    for (int off = 1; off < 256; off <<= 1) {
        int tmp = (t >= off) ? sdata[t - off] : 0;
        __syncthreads();
        val += tmp;
        sdata[t] = val;
        __syncthreads();
    }
    if (t < NB) bktBase[t] = val - s;
    if (t == 0) bktBase[NB] = N_EDGES;
}

// Phase B: scatter edges into bucket regions; positions pre-reserved per
// (block,bucket) so writes form contiguous runs -> full-line writebacks.
__global__ __launch_bounds__(256) void k_phaseB(const int* __restrict__ src,
                                                const int* __restrict__ dst,
                                                const int* __restrict__ Cm,
                                                const int* __restrict__ bktBase,
                                                unsigned int* __restrict__ bucketed) {
    __shared__ int offs[NB];
    int blk = blockIdx.x, t = threadIdx.x;
    if (t < NB) offs[t] = Cm[blk * NB + t] + bktBase[t];
    __syncthreads();
    int base = blk * EPB;
#pragma unroll 5
    for (int k = 0; k < EPB / 256; k++) {
        int e = base + k * 256 + t;
        int d = dst[e];
        int sv = src[e];
        int pos = atomicAdd(&offs[d >> 9], 1);
        bucketed[pos] = ((unsigned int)sv << 9) | (unsigned int)(d & 511);
    }
}

// Phase C: one block per bucket. LDS histogram + scan -> rowptr/dinv slices
// (coalesced) + fine scatter of csr_src within the bucket's own region
// (single-XCD, L2-assembled lines).
__global__ __launch_bounds__(512) void k_phaseC(const unsigned int* __restrict__ bucketed,
                                                const int* __restrict__ bktBase,
                                                int* __restrict__ rowptr,
                                                float* __restrict__ dinvg,
                                                int* __restrict__ csr_src) {
    __shared__ int cnt[512];
    __shared__ int cur[512];
    __shared__ int sdata[512];
    int b = blockIdx.x, t = threadIdx.x;
    int base = bktBase[b], endR = bktBase[b + 1];
    int nodeBase = b << 9;
    int nNodes = N_NODES - nodeBase;
    if (nNodes > 512) nNodes = 512;

    cnt[t] = 0;
    __syncthreads();
    for (int e = base + t; e < endR; e += 512)
        atomicAdd(&cnt[bucketed[e] & 511], 1);
    __syncthreads();

    int s = cnt[t];
    sdata[t] = s;
    __syncthreads();
    int val = s;
    for (int off = 1; off < 512; off <<= 1) {
        int tmp = (t >= off) ? sdata[t - off] : 0;
        __syncthreads();
        val += tmp;
        sdata[t] = val;
        __syncthreads();
    }
    cur[t] = val - s;
    if (t < nNodes) {
        rowptr[nodeBase + t] = base + val - s;
        dinvg[nodeBase + t] = rsqrtf((float)s + 1.0f);
    }
    if (b == NB - 1 && t == 0) rowptr[N_NODES] = N_EDGES;
    __syncthreads();

    for (int e = base + t; e < endR; e += 512) {
        unsigned int u = bucketed[e];
        int pos = base + atomicAdd(&cur[u & 511], 1);
        csr_src[pos] = (int)(u >> 9);
    }
}

// ---------------- dense GEMM (f32 in, bf16 out, K=128 fixed) ----------------

__global__ __launch_bounds__(256) void k_pack(const float* __restrict__ Wmu,
                                              const float* __restrict__ Wls,
                                              float* __restrict__ Wcat) {
    int idx = blockIdx.x * 256 + threadIdx.x;
    if (idx < 128 * 128) {
        int k = idx >> 7, c = idx & 127;
        Wcat[idx] = (c < 64) ? Wmu[k * 64 + c] : Wls[k * 64 + (c - 64)];
    }
}

#define GROWS 32
__global__ __launch_bounds__(256) void k_gemm(const float* __restrict__ X,
                                              const float* __restrict__ W,
                                              unsigned short* __restrict__ Y) {
    __shared__ float sW[128 * 128];   // 64 KiB
    __shared__ float sX[GROWS * 128]; // 16 KiB
    int t = threadIdx.x;
    {
        const float4* W4 = (const float4*)W;
        float4* sW4 = (float4*)sW;
#pragma unroll
        for (int j = 0; j < 16; j++) sW4[t + 256 * j] = W4[t + 256 * j];
        const float4* X4 = (const float4*)(X + (size_t)blockIdx.x * GROWS * 128);
        float4* sX4 = (float4*)sX;
#pragma unroll
        for (int j = 0; j < 4; j++) sX4[t + 256 * j] = X4[t + 256 * j];
    }
    __syncthreads();

    int tx = t & 31;
    int ty = t >> 5;
    float acc[4][4] = {};

#pragma unroll 2
    for (int k0 = 0; k0 < 128; k0 += 4) {
        float4 xq[4];
#pragma unroll
        for (int r = 0; r < 4; r++)
            xq[r] = *(const float4*)&sX[(ty * 4 + r) * 128 + k0];
#pragma unroll
        for (int kk = 0; kk < 4; kk++) {
            float4 w = *(const float4*)&sW[(k0 + kk) * 128 + tx * 4];
#pragma unroll
            for (int r = 0; r < 4; r++) {
                float xv = ((const float*)&xq[r])[kk];
                acc[r][0] = fmaf(xv, w.x, acc[r][0]);
                acc[r][1] = fmaf(xv, w.y, acc[r][1]);
                acc[r][2] = fmaf(xv, w.z, acc[r][2]);
                acc[r][3] = fmaf(xv, w.w, acc[r][3]);
            }
        }
    }
    unsigned short* Yb = Y + (size_t)blockIdx.x * GROWS * 128;
#pragma unroll
    for (int r = 0; r < 4; r++) {
        ushort4 o;
        o.x = f2bf(acc[r][0]);
        o.y = f2bf(acc[r][1]);
        o.z = f2bf(acc[r][2]);
        o.w = f2bf(acc[r][3]);
        *(ushort4*)&Yb[(ty * 4 + r) * 128 + tx * 4] = o;
    }
}

// ---------------- aggregations (CSR gather, one wave per node, unroll 8) ----

__global__ __launch_bounds__(256) void k_agg1(const unsigned short* __restrict__ h0,
                                              const int* __restrict__ rowptr,
                                              const int* __restrict__ csr_src,
                                              const float* __restrict__ dinv,
                                              const float* __restrict__ b1,
                                              float* __restrict__ h) {
    int lane = threadIdx.x & 63;
    int i = __builtin_amdgcn_readfirstlane(blockIdx.x * 4 + (threadIdx.x >> 6));
    int c2 = lane * 2;
    float di = dinv[i];
    unsigned int sv = *(const unsigned int*)(h0 + (size_t)i * 128 + c2);
    float ax = bfl(sv) * di * di, ay = bfh(sv) * di * di;
    int beg = rowptr[i], end = rowptr[i + 1];
    for (int p = beg; p < end; p += 8) {
        int s[8]; float n[8]; unsigned int r[8];
#pragma unroll
        for (int j = 0; j < 8; j++) {
            int q = p + j;
            s[j] = csr_src[q < end ? q : end - 1];
        }
#pragma unroll
        for (int j = 0; j < 8; j++) n[j] = dinv[s[j]];
#pragma unroll
        for (int j = 0; j < 8; j++)
            r[j] = *(const unsigned int*)(h0 + (size_t)s[j] * 128 + c2);
#pragma unroll
        for (int j = 0; j < 8; j++) n[j] = (p + j < end) ? n[j] * di : 0.f;
#pragma unroll
        for (int j = 0; j < 8; j++) {
            ax = fmaf(bfl(r[j]), n[j], ax);
            ay = fmaf(bfh(r[j]), n[j], ay);
        }
    }
    ax += b1[c2];
    ay += b1[c2 + 1];
    ax = ax > 0.f ? ax : 0.f;
    ay = ay > 0.f ? ay : 0.f;
    *(float2*)(h + (size_t)i * 128 + c2) = make_float2(ax, ay);
}

__global__ __launch_bounds__(256) void k_agg2(const unsigned short* __restrict__ tt,
                                              const int* __restrict__ rowptr,
                                              const int* __restrict__ csr_src,
                                              const float* __restrict__ dinv,
                                              const float* __restrict__ bmu,
                                              const float* __restrict__ bls,
                                              float* __restrict__ out) {
    int lane = threadIdx.x & 63;
    int i = __builtin_amdgcn_readfirstlane(blockIdx.x * 4 + (threadIdx.x >> 6));
    int c2 = lane * 2;
    float di = dinv[i];
    unsigned int sv = *(const unsigned int*)(tt + (size_t)i * 128 + c2);
    float ax = bfl(sv) * di * di, ay = bfh(sv) * di * di;
    int beg = rowptr[i], end = rowptr[i + 1];
    for (int p = beg; p < end; p += 8) {
        int s[8]; float n[8]; unsigned int r[8];
#pragma unroll
        for (int j = 0; j < 8; j++) {
            int q = p + j;
            s[j] = csr_src[q < end ? q : end - 1];
        }
#pragma unroll
        for (int j = 0; j < 8; j++) n[j] = dinv[s[j]];
#pragma unroll
        for (int j = 0; j < 8; j++)
            r[j] = *(const unsigned int*)(tt + (size_t)s[j] * 128 + c2);
#pragma unroll
        for (int j = 0; j < 8; j++) n[j] = (p + j < end) ? n[j] * di : 0.f;
#pragma unroll
        for (int j = 0; j < 8; j++) {
            ax = fmaf(bfl(r[j]), n[j], ax);
            ay = fmaf(bfh(r[j]), n[j], ay);
        }
    }
    if (lane < 32) {
        int c = c2;                       // mu channels 0..63
        *(float2*)(out + (size_t)i * 64 + c) =
            make_float2(ax + bmu[c], ay + bmu[c + 1]);
    } else {
        int c = c2 - 64;                  // logstd channels 0..63
        *(float2*)(out + (size_t)N_NODES * 64 + (size_t)i * 64 + c) =
            make_float2(ax + bls[c], ay + bls[c + 1]);
    }
}

// ---------------- launch ----------------

extern "C" void kernel_launch(void* const* d_in, const int* in_sizes, int n_in,
                              void* d_out, int out_size, void* d_ws, size_t ws_size,
                              hipStream_t stream) {
    const float* x    = (const float*)d_in[0];
    const int*   ei   = (const int*)d_in[1];
    const float* W1   = (const float*)d_in[2];
    const float* b1   = (const float*)d_in[3];
    const float* Wmu  = (const float*)d_in[4];
    const float* bmu  = (const float*)d_in[5];
    const float* Wls  = (const float*)d_in[6];
    const float* bls  = (const float*)d_in[7];
    const int* src = ei;
    const int* dst = ei + N_EDGES;

    char* p = (char*)d_ws;
    unsigned short* bufA = (unsigned short*)p; p += (size_t)N_NODES * 128 * 2; // 25.6 MB bf16: h0 / t
    float* bufB    = (float*)p; p += (size_t)N_NODES * 128 * 4;                // 51.2 MB f32: h
    float* Wcat    = (float*)p; p += 128 * 128 * 4;
    int*   Cm      = (int*)p;   p += (size_t)NBLK * NB * 4;                    // 196 KB
    int*   bktBase = (int*)p;   p += 256 * 4;
    int*   rowptr  = (int*)p;   p += 400016;
    float* dinv    = (float*)p; p += 400000;
    unsigned int* bucketed = (unsigned int*)p; p += (size_t)N_EDGES * 4;       // 6.4 MB
    int*   csr_src = (int*)p;   p += (size_t)N_EDGES * 4;                      // 6.4 MB

    // CSR build (no global atomics, write-coalesced)
    k_phaseA<<<NBLK, 256, 0, stream>>>(dst, Cm);
    k_scanCm<<<1, 256, 0, stream>>>(Cm, bktBase);
    k_phaseB<<<NBLK, 256, 0, stream>>>(src, dst, Cm, bktBase, bucketed);
    k_phaseC<<<NB, 512, 0, stream>>>(bucketed, bktBase, rowptr, dinv, csr_src);

    k_pack<<<64, 256, 0, stream>>>(Wmu, Wls, Wcat);

    // layer 1: h0 = x @ W1 (bf16) ; h = relu(agg(h0) + b1) (f32)
    k_gemm<<<N_NODES / GROWS, 256, 0, stream>>>(x, W1, bufA);
    k_agg1<<<N_NODES / 4, 256, 0, stream>>>(bufA, rowptr, csr_src, dinv, b1, bufB);

    // layer 2: t = h @ [Wmu|Wls] (bf16) ; out = agg(t) + bias (f32)
    k_gemm<<<N_NODES / GROWS, 256, 0, stream>>>(bufB, Wcat, bufA);
    k_agg2<<<N_NODES / 4, 256, 0, stream>>>(bufA, rowptr, csr_src, dinv,
                                            bmu, bls, (float*)d_out);
}

// Round 4
// 353.176 us; speedup vs baseline: 2.0782x; 1.1305x over previous
//
#include <hip/hip_runtime.h>
#include <hip/hip_bf16.h>
#include <stdint.h>

#define N_NODES 100000
#define IN_CH   128
#define HID     128
#define OUT_CH  64
#define N_EDGES 1600000

#define NB    196      // buckets of 512 nodes
#define NBLK  250      // edge-partition blocks for phases A/B
#define EPB   6400     // edges per block

typedef __attribute__((ext_vector_type(8))) short  bf16x8;
typedef __attribute__((ext_vector_type(4))) float  f32x4;

// ---------------- helpers ----------------

__device__ __forceinline__ unsigned short f2bf(float f) {   // RNE f32->bf16
    unsigned int u = __float_as_uint(f);
    u = (u + 0x7fffu + ((u >> 16) & 1u)) >> 16;
    return (unsigned short)u;
}
__device__ __forceinline__ float bfl(unsigned int u) { return __uint_as_float(u << 16); }
__device__ __forceinline__ float bfh(unsigned int u) { return __uint_as_float(u & 0xffff0000u); }

// ---------------- CSR build: bucket sort (unchanged from R3) ----------------

__global__ __launch_bounds__(256) void k_phaseA(const int* __restrict__ dst,
                                                int* __restrict__ Cm) {
    __shared__ int hist[NB];
    int blk = blockIdx.x, t = threadIdx.x;
    if (t < NB) hist[t] = 0;
    __syncthreads();
    int base = blk * EPB;
#pragma unroll 5
    for (int k = 0; k < EPB / 256; k++) {
        int d = dst[base + k * 256 + t];
        atomicAdd(&hist[d >> 9], 1);
    }
    __syncthreads();
    if (t < NB) Cm[blk * NB + t] = hist[t];
}

__global__ __launch_bounds__(256) void k_scanCm(int* __restrict__ Cm,
                                                int* __restrict__ bktBase) {
    __shared__ int sdata[256];
    int t = threadIdx.x;
    int run = 0;
    if (t < NB) {
        for (int blk = 0; blk < NBLK; blk++) {
            int idx = blk * NB + t;
            int v = Cm[idx];
            Cm[idx] = run;
            run += v;
        }
    }
    int s = (t < NB) ? run : 0;
    sdata[t] = s;
    __syncthreads();
    int val = s;
    for (int off = 1; off < 256; off <<= 1) {
        int tmp = (t >= off) ? sdata[t - off] : 0;
        __syncthreads();
        val += tmp;
        sdata[t] = val;
        __syncthreads();
    }
    if (t < NB) bktBase[t] = val - s;
    if (t == 0) bktBase[NB] = N_EDGES;
}

__global__ __launch_bounds__(256) void k_phaseB(const int* __restrict__ src,
                                                const int* __restrict__ dst,
                                                const int* __restrict__ Cm,
                                                const int* __restrict__ bktBase,
                                                unsigned int* __restrict__ bucketed) {
    __shared__ int offs[NB];
    int blk = blockIdx.x, t = threadIdx.x;
    if (t < NB) offs[t] = Cm[blk * NB + t] + bktBase[t];
    __syncthreads();
    int base = blk * EPB;
#pragma unroll 5
    for (int k = 0; k < EPB / 256; k++) {
        int e = base + k * 256 + t;
        int d = dst[e];
        int sv = src[e];
        int pos = atomicAdd(&offs[d >> 9], 1);
        bucketed[pos] = ((unsigned int)sv << 9) | (unsigned int)(d & 511);
    }
}

__global__ __launch_bounds__(512) void k_phaseC(const unsigned int* __restrict__ bucketed,
                                                const int* __restrict__ bktBase,
                                                int* __restrict__ rowptr,
                                                float* __restrict__ dinvg,
                                                int* __restrict__ csr_src) {
    __shared__ int cnt[512];
    __shared__ int cur[512];
    __shared__ int sdata[512];
    int b = blockIdx.x, t = threadIdx.x;
    int base = bktBase[b], endR = bktBase[b + 1];
    int nodeBase = b << 9;
    int nNodes = N_NODES - nodeBase;
    if (nNodes > 512) nNodes = 512;

    cnt[t] = 0;
    __syncthreads();
    for (int e = base + t; e < endR; e += 512)
        atomicAdd(&cnt[bucketed[e] & 511], 1);
    __syncthreads();

    int s = cnt[t];
    sdata[t] = s;
    __syncthreads();
    int val = s;
    for (int off = 1; off < 512; off <<= 1) {
        int tmp = (t >= off) ? sdata[t - off] : 0;
        __syncthreads();
        val += tmp;
        sdata[t] = val;
        __syncthreads();
    }
    cur[t] = val - s;
    if (t < nNodes) {
        rowptr[nodeBase + t] = base + val - s;
        dinvg[nodeBase + t] = rsqrtf((float)s + 1.0f);
    }
    if (b == NB - 1 && t == 0) rowptr[N_NODES] = N_EDGES;
    __syncthreads();

    for (int e = base + t; e < endR; e += 512) {
        unsigned int u = bucketed[e];
        int pos = base + atomicAdd(&cur[u & 511], 1);
        csr_src[pos] = (int)(u >> 9);
    }
}

// ---------------- W prep: transpose to bf16 [n][k], fuse mu|ls concat -------

__global__ __launch_bounds__(256) void k_prepW(const float* __restrict__ W1,
                                               const float* __restrict__ Wmu,
                                               const float* __restrict__ Wls,
                                               unsigned short* __restrict__ Wt1,
                                               unsigned short* __restrict__ WtC) {
    int idx = blockIdx.x * 256 + threadIdx.x;   // 64 blocks * 256 = 16384
    int n = idx >> 7, k = idx & 127;
    Wt1[idx] = f2bf(W1[k * 128 + n]);
    WtC[idx] = f2bf((n < 64) ? Wmu[k * 64 + n] : Wls[k * 64 + (n - 64)]);
}

// ---------------- MFMA GEMM: [M x 128] @ [128 x 128] -> bf16 ----------------
// Block = 128 rows x 128 cols, K=128 fully staged. A in LDS (stride 136 bf16),
// B fragments straight from the 32 KB L1-resident Wt table.

#define LDA 136

__device__ __forceinline__ void gemm_compute(const unsigned short* sA,
                                             const unsigned short* __restrict__ Wt,
                                             unsigned short* __restrict__ Y,
                                             int R0, int t) {
    int wv = t >> 6, l = t & 63;
    int quad = l >> 4, lm = l & 15;

    bf16x8 a[2][4];
#pragma unroll
    for (int mt = 0; mt < 2; mt++)
#pragma unroll
        for (int ks = 0; ks < 4; ks++)
            a[mt][ks] = *(const bf16x8*)(sA + (wv * 32 + mt * 16 + lm) * LDA +
                                         ks * 32 + quad * 8);

    f32x4 acc[2][8] = {};
#pragma unroll
    for (int nt = 0; nt < 8; nt++) {
        bf16x8 b[4];
        const unsigned short* Wp = Wt + (nt * 16 + lm) * 128 + quad * 8;
#pragma unroll
        for (int ks = 0; ks < 4; ks++)
            b[ks] = *(const bf16x8*)(Wp + ks * 32);
#pragma unroll
        for (int mt = 0; mt < 2; mt++) {
            f32x4 c = acc[mt][nt];
#pragma unroll
            for (int ks = 0; ks < 4; ks++)
                c = __builtin_amdgcn_mfma_f32_16x16x32_bf16(a[mt][ks], b[ks], c, 0, 0, 0);
            acc[mt][nt] = c;
        }
    }

    int rbase = R0 + wv * 32 + quad * 4;
#pragma unroll
    for (int mt = 0; mt < 2; mt++)
#pragma unroll
        for (int nt = 0; nt < 8; nt++)
#pragma unroll
            for (int reg = 0; reg < 4; reg++) {
                int row = rbase + mt * 16 + reg;
                if (row < N_NODES)
                    Y[(size_t)row * 128 + nt * 16 + lm] = f2bf(acc[mt][nt][reg]);
            }
}

// A from f32 input
__global__ __launch_bounds__(256) void k_gemm1(const float* __restrict__ X,
                                               const unsigned short* __restrict__ Wt,
                                               unsigned short* __restrict__ Y) {
    __shared__ unsigned short sA[128 * LDA];
    int t = threadIdx.x;
    int R0 = blockIdx.x * 128;
    int row = t >> 1, colb = (t & 1) * 64;
    bool valid = (R0 + row) < N_NODES;
    const float* Xr = X + (size_t)(R0 + row) * 128 + colb;
    unsigned short* dp = sA + row * LDA + colb;
#pragma unroll
    for (int j = 0; j < 16; j++) {
        float4 v = valid ? *(const float4*)(Xr + j * 4) : make_float4(0.f, 0.f, 0.f, 0.f);
        ushort4 o;
        o.x = f2bf(v.x); o.y = f2bf(v.y); o.z = f2bf(v.z); o.w = f2bf(v.w);
        *(ushort4*)(dp + j * 4) = o;
    }
    __syncthreads();
    gemm_compute(sA, Wt, Y, R0, t);
}

// A from bf16 input
__global__ __launch_bounds__(256) void k_gemm2(const unsigned short* __restrict__ Xb,
                                               const unsigned short* __restrict__ Wt,
                                               unsigned short* __restrict__ Y) {
    __shared__ unsigned short sA[128 * LDA];
    int t = threadIdx.x;
    int R0 = blockIdx.x * 128;
    int row = t >> 1, colb = (t & 1) * 64;
    bool valid = (R0 + row) < N_NODES;
    const unsigned short* Xr = Xb + (size_t)(R0 + row) * 128 + colb;
    unsigned short* dp = sA + row * LDA + colb;
#pragma unroll
    for (int j = 0; j < 8; j++) {
        uint4 v = valid ? *(const uint4*)(Xr + j * 8) : make_uint4(0u, 0u, 0u, 0u);
        *(uint4*)(dp + j * 8) = v;
    }
    __syncthreads();
    gemm_compute(sA, Wt, Y, R0, t);
}

// ---------------- aggregations (CSR gather, one wave per node, unroll 8) ----

__global__ __launch_bounds__(256) void k_agg1(const unsigned short* __restrict__ h0,
                                              const int* __restrict__ rowptr,
                                              const int* __restrict__ csr_src,
                                              const float* __restrict__ dinv,
                                              const float* __restrict__ b1,
                                              unsigned short* __restrict__ hb) {
    int lane = threadIdx.x & 63;
    int i = __builtin_amdgcn_readfirstlane(blockIdx.x * 4 + (threadIdx.x >> 6));
    int c2 = lane * 2;
    float di = dinv[i];
    unsigned int sv = *(const unsigned int*)(h0 + (size_t)i * 128 + c2);
    float ax = bfl(sv) * di * di, ay = bfh(sv) * di * di;
    int beg = rowptr[i], end = rowptr[i + 1];
    for (int p = beg; p < end; p += 8) {
        int s[8]; float n[8]; unsigned int r[8];
#pragma unroll
        for (int j = 0; j < 8; j++) {
            int q = p + j;
            s[j] = csr_src[q < end ? q : end - 1];
        }
#pragma unroll
        for (int j = 0; j < 8; j++) n[j] = dinv[s[j]];
#pragma unroll
        for (int j = 0; j < 8; j++)
            r[j] = *(const unsigned int*)(h0 + (size_t)s[j] * 128 + c2);
#pragma unroll
        for (int j = 0; j < 8; j++) n[j] = (p + j < end) ? n[j] * di : 0.f;
#pragma unroll
        for (int j = 0; j < 8; j++) {
            ax = fmaf(bfl(r[j]), n[j], ax);
            ay = fmaf(bfh(r[j]), n[j], ay);
        }
    }
    ax += b1[c2];
    ay += b1[c2 + 1];
    ax = ax > 0.f ? ax : 0.f;
    ay = ay > 0.f ? ay : 0.f;
    // bf16 output: GEMM2 rounds to bf16 anyway -> zero extra error, half traffic
    unsigned int pk = ((unsigned int)f2bf(ay) << 16) | (unsigned int)f2bf(ax);
    *(unsigned int*)(hb + (size_t)i * 128 + c2) = pk;
}

__global__ __launch_bounds__(256) void k_agg2(const unsigned short* __restrict__ tt,
                                              const int* __restrict__ rowptr,
                                              const int* __restrict__ csr_src,
                                              const float* __restrict__ dinv,
                                              const float* __restrict__ bmu,
                                              const float* __restrict__ bls,
                                              float* __restrict__ out) {
    int lane = threadIdx.x & 63;
    int i = __builtin_amdgcn_readfirstlane(blockIdx.x * 4 + (threadIdx.x >> 6));
    int c2 = lane * 2;
    float di = dinv[i];
    unsigned int sv = *(const unsigned int*)(tt + (size_t)i * 128 + c2);
    float ax = bfl(sv) * di * di, ay = bfh(sv) * di * di;
    int beg = rowptr[i], end = rowptr[i + 1];
    for (int p = beg; p < end; p += 8) {
        int s[8]; float n[8]; unsigned int r[8];
#pragma unroll
        for (int j = 0; j < 8; j++) {
            int q = p + j;
            s[j] = csr_src[q < end ? q : end - 1];
        }
#pragma unroll
        for (int j = 0; j < 8; j++) n[j] = dinv[s[j]];
#pragma unroll
        for (int j = 0; j < 8; j++)
            r[j] = *(const unsigned int*)(tt + (size_t)s[j] * 128 + c2);
#pragma unroll
        for (int j = 0; j < 8; j++) n[j] = (p + j < end) ? n[j] * di : 0.f;
#pragma unroll
        for (int j = 0; j < 8; j++) {
            ax = fmaf(bfl(r[j]), n[j], ax);
            ay = fmaf(bfh(r[j]), n[j], ay);
        }
    }
    if (lane < 32) {
        int c = c2;                       // mu channels 0..63
        *(float2*)(out + (size_t)i * 64 + c) =
            make_float2(ax + bmu[c], ay + bmu[c + 1]);
    } else {
        int c = c2 - 64;                  // logstd channels 0..63
        *(float2*)(out + (size_t)N_NODES * 64 + (size_t)i * 64 + c) =
            make_float2(ax + bls[c], ay + bls[c + 1]);
    }
}

// ---------------- launch ----------------

extern "C" void kernel_launch(void* const* d_in, const int* in_sizes, int n_in,
                              void* d_out, int out_size, void* d_ws, size_t ws_size,
                              hipStream_t stream) {
    const float* x    = (const float*)d_in[0];
    const int*   ei   = (const int*)d_in[1];
    const float* W1   = (const float*)d_in[2];
    const float* b1   = (const float*)d_in[3];
    const float* Wmu  = (const float*)d_in[4];
    const float* bmu  = (const float*)d_in[5];
    const float* Wls  = (const float*)d_in[6];
    const float* bls  = (const float*)d_in[7];
    const int* src = ei;
    const int* dst = ei + N_EDGES;

    char* p = (char*)d_ws;
    unsigned short* bufA = (unsigned short*)p; p += (size_t)N_NODES * 128 * 2; // 25.6 MB bf16: h0 / t
    unsigned short* bufH = (unsigned short*)p; p += (size_t)N_NODES * 128 * 2; // 25.6 MB bf16: h
    unsigned short* Wt1  = (unsigned short*)p; p += 128 * 128 * 2;
    unsigned short* WtC  = (unsigned short*)p; p += 128 * 128 * 2;
    int*   Cm      = (int*)p;   p += (size_t)NBLK * NB * 4;
    int*   bktBase = (int*)p;   p += 256 * 4;
    int*   rowptr  = (int*)p;   p += 400016;
    float* dinv    = (float*)p; p += 400000;
    unsigned int* bucketed = (unsigned int*)p; p += (size_t)N_EDGES * 4;
    int*   csr_src = (int*)p;   p += (size_t)N_EDGES * 4;

    // CSR build (no global atomics, write-coalesced)
    k_phaseA<<<NBLK, 256, 0, stream>>>(dst, Cm);
    k_scanCm<<<1, 256, 0, stream>>>(Cm, bktBase);
    k_phaseB<<<NBLK, 256, 0, stream>>>(src, dst, Cm, bktBase, bucketed);
    k_phaseC<<<NB, 512, 0, stream>>>(bucketed, bktBase, rowptr, dinv, csr_src);

    k_prepW<<<64, 256, 0, stream>>>(W1, Wmu, Wls, Wt1, WtC);

    int gblk = (N_NODES + 127) / 128;   // 782

    // layer 1: h0 = x @ W1 (MFMA bf16) ; h = relu(agg(h0) + b1) (bf16 out)
    k_gemm1<<<gblk, 256, 0, stream>>>(x, Wt1, bufA);
    k_agg1<<<N_NODES / 4, 256, 0, stream>>>(bufA, rowptr, csr_src, dinv, b1, bufH);

    // layer 2: t = h @ [Wmu|Wls] (MFMA bf16) ; out = agg(t) + bias
    k_gemm2<<<gblk, 256, 0, stream>>>(bufH, WtC, bufA);
    k_agg2<<<N_NODES / 4, 256, 0, stream>>>(bufA, rowptr, csr_src, dinv,
                                            bmu, bls, (float*)d_out);
}

// Round 5
// 343.156 us; speedup vs baseline: 2.1389x; 1.0292x over previous
//
#include <hip/hip_runtime.h>
#include <hip/hip_bf16.h>
#include <stdint.h>

#define N_NODES 100000
#define IN_CH   128
#define HID     128
#define OUT_CH  64
#define N_EDGES 1600000

#define NB    196      // buckets of 512 nodes
#define NBLK  250      // edge-partition blocks for phases A/B
#define EPB   6400     // edges per block

typedef __attribute__((ext_vector_type(8))) short  bf16x8;
typedef __attribute__((ext_vector_type(4))) float  f32x4;

// ---------------- helpers ----------------

__device__ __forceinline__ unsigned short f2bf(float f) {   // RNE f32->bf16
    unsigned int u = __float_as_uint(f);
    u = (u + 0x7fffu + ((u >> 16) & 1u)) >> 16;
    return (unsigned short)u;
}
__device__ __forceinline__ float bfl(unsigned int u) { return __uint_as_float(u << 16); }
__device__ __forceinline__ float bfh(unsigned int u) { return __uint_as_float(u & 0xffff0000u); }

// ---------------- CSR build: bucket sort ----------------

__global__ __launch_bounds__(256) void k_phaseA(const int* __restrict__ dst,
                                                int* __restrict__ Cm) {
    __shared__ int hist[NB];
    int blk = blockIdx.x, t = threadIdx.x;
    if (t < NB) hist[t] = 0;
    __syncthreads();
    int base = blk * EPB;
#pragma unroll 5
    for (int k = 0; k < EPB / 256; k++) {
        int d = dst[base + k * 256 + t];
        atomicAdd(&hist[d >> 9], 1);
    }
    __syncthreads();
    if (t < NB) Cm[blk * NB + t] = hist[t];
}

// parallel scan of Cm over blocks: one block per bucket
__global__ __launch_bounds__(256) void k_scanBkt(int* __restrict__ Cm,
                                                 int* __restrict__ bktSum) {
    __shared__ int sdata[256];
    int b = blockIdx.x, t = threadIdx.x;
    int v = (t < NBLK) ? Cm[t * NB + b] : 0;
    sdata[t] = v;
    __syncthreads();
    int val = v;
    for (int off = 1; off < 256; off <<= 1) {
        int tmp = (t >= off) ? sdata[t - off] : 0;
        __syncthreads();
        val += tmp;
        sdata[t] = val;
        __syncthreads();
    }
    if (t < NBLK) Cm[t * NB + b] = val - v;   // exclusive prefix within bucket
    if (t == 255) bktSum[b] = val;
}

__global__ __launch_bounds__(256) void k_scanBase(const int* __restrict__ bktSum,
                                                  int* __restrict__ bktBase) {
    __shared__ int sdata[256];
    int t = threadIdx.x;
    int v = (t < NB) ? bktSum[t] : 0;
    sdata[t] = v;
    __syncthreads();
    int val = v;
    for (int off = 1; off < 256; off <<= 1) {
        int tmp = (t >= off) ? sdata[t - off] : 0;
        __syncthreads();
        val += tmp;
        sdata[t] = val;
        __syncthreads();
    }
    if (t < NB) bktBase[t] = val - v;
    if (t == 0) bktBase[NB] = N_EDGES;
}

__global__ __launch_bounds__(256) void k_phaseB(const int* __restrict__ src,
                                                const int* __restrict__ dst,
                                                const int* __restrict__ Cm,
                                                const int* __restrict__ bktBase,
                                                unsigned int* __restrict__ bucketed) {
    __shared__ int offs[NB];
    int blk = blockIdx.x, t = threadIdx.x;
    if (t < NB) offs[t] = Cm[blk * NB + t] + bktBase[t];
    __syncthreads();
    int base = blk * EPB;
#pragma unroll 5
    for (int k = 0; k < EPB / 256; k++) {
        int e = base + k * 256 + t;
        int d = dst[e];
        int sv = src[e];
        int pos = atomicAdd(&offs[d >> 9], 1);
        bucketed[pos] = ((unsigned int)sv << 9) | (unsigned int)(d & 511);
    }
}

__global__ __launch_bounds__(512) void k_phaseC(const unsigned int* __restrict__ bucketed,
                                                const int* __restrict__ bktBase,
                                                int* __restrict__ rowptr,
                                                float* __restrict__ dinvg,
                                                int* __restrict__ csr_src) {
    __shared__ int cnt[512];
    __shared__ int cur[512];
    __shared__ int sdata[512];
    int b = blockIdx.x, t = threadIdx.x;
    int base = bktBase[b], endR = bktBase[b + 1];
    int nodeBase = b << 9;
    int nNodes = N_NODES - nodeBase;
    if (nNodes > 512) nNodes = 512;

    cnt[t] = 0;
    __syncthreads();
    for (int e = base + t; e < endR; e += 512)
        atomicAdd(&cnt[bucketed[e] & 511], 1);
    __syncthreads();

    int s = cnt[t];
    sdata[t] = s;
    __syncthreads();
    int val = s;
    for (int off = 1; off < 512; off <<= 1) {
        int tmp = (t >= off) ? sdata[t - off] : 0;
        __syncthreads();
        val += tmp;
        sdata[t] = val;
        __syncthreads();
    }
    cur[t] = val - s;
    if (t < nNodes) {
        rowptr[nodeBase + t] = base + val - s;
        dinvg[nodeBase + t] = rsqrtf((float)s + 1.0f);
    }
    if (b == NB - 1 && t == 0) rowptr[N_NODES] = N_EDGES;
    __syncthreads();

    for (int e = base + t; e < endR; e += 512) {
        unsigned int u = bucketed[e];
        int pos = base + atomicAdd(&cur[u & 511], 1);
        csr_src[pos] = (int)(u >> 9);
    }
}

// ---------------- W prep: transpose to bf16 [n][k], fuse mu|ls concat -------

__global__ __launch_bounds__(256) void k_prepW(const float* __restrict__ W1,
                                               const float* __restrict__ Wmu,
                                               const float* __restrict__ Wls,
                                               unsigned short* __restrict__ Wt1,
                                               unsigned short* __restrict__ WtC) {
    int idx = blockIdx.x * 256 + threadIdx.x;
    int n = idx >> 7, k = idx & 127;
    Wt1[idx] = f2bf(W1[k * 128 + n]);
    WtC[idx] = f2bf((n < 64) ? Wmu[k * 64 + n] : Wls[k * 64 + (n - 64)]);
}

// ---------------- MFMA GEMM1: x[f32] @ W1 -> h0[bf16] ----------------------

#define LDA 136

__global__ __launch_bounds__(256) void k_gemm1(const float* __restrict__ X,
                                               const unsigned short* __restrict__ Wt,
                                               unsigned short* __restrict__ Y) {
    __shared__ unsigned short sA[128 * LDA];
    int t = threadIdx.x;
    int R0 = blockIdx.x * 128;
    int row = t >> 1, colb = (t & 1) * 64;
    bool valid = (R0 + row) < N_NODES;
    const float* Xr = X + (size_t)(R0 + row) * 128 + colb;
    unsigned short* dp = sA + row * LDA + colb;
#pragma unroll
    for (int j = 0; j < 16; j++) {
        float4 v = valid ? *(const float4*)(Xr + j * 4) : make_float4(0.f, 0.f, 0.f, 0.f);
        ushort4 o;
        o.x = f2bf(v.x); o.y = f2bf(v.y); o.z = f2bf(v.z); o.w = f2bf(v.w);
        *(ushort4*)(dp + j * 4) = o;
    }
    __syncthreads();

    int wv = t >> 6, l = t & 63;
    int quad = l >> 4, lm = l & 15;

    bf16x8 a[2][4];
#pragma unroll
    for (int mt = 0; mt < 2; mt++)
#pragma unroll
        for (int ks = 0; ks < 4; ks++)
            a[mt][ks] = *(const bf16x8*)(sA + (wv * 32 + mt * 16 + lm) * LDA +
                                         ks * 32 + quad * 8);

    f32x4 acc[2][8] = {};
#pragma unroll
    for (int nt = 0; nt < 8; nt++) {
        bf16x8 b[4];
        const unsigned short* Wp = Wt + (nt * 16 + lm) * 128 + quad * 8;
#pragma unroll
        for (int ks = 0; ks < 4; ks++)
            b[ks] = *(const bf16x8*)(Wp + ks * 32);
#pragma unroll
        for (int mt = 0; mt < 2; mt++) {
            f32x4 c = acc[mt][nt];
#pragma unroll
            for (int ks = 0; ks < 4; ks++)
                c = __builtin_amdgcn_mfma_f32_16x16x32_bf16(a[mt][ks], b[ks], c, 0, 0, 0);
            acc[mt][nt] = c;
        }
    }

    int rbase = R0 + wv * 32 + quad * 4;
#pragma unroll
    for (int mt = 0; mt < 2; mt++)
#pragma unroll
        for (int nt = 0; nt < 8; nt++)
#pragma unroll
            for (int reg = 0; reg < 4; reg++) {
                int r = rbase + mt * 16 + reg;
                if (r < N_NODES)
                    Y[(size_t)r * 128 + nt * 16 + lm] = f2bf(acc[mt][nt][reg]);
            }
}

// ---------------- agg1: h = relu(agg(h0)+b1), bf16 out, unroll 16 ----------

__global__ __launch_bounds__(256) void k_agg1(const unsigned short* __restrict__ h0,
                                              const int* __restrict__ rowptr,
                                              const int* __restrict__ csr_src,
                                              const float* __restrict__ dinv,
                                              const float* __restrict__ b1,
                                              unsigned short* __restrict__ hb) {
    int lane = threadIdx.x & 63;
    int i = __builtin_amdgcn_readfirstlane(blockIdx.x * 4 + (threadIdx.x >> 6));
    int c2 = lane * 2;
    float di = dinv[i];
    unsigned int sv = *(const unsigned int*)(h0 + (size_t)i * 128 + c2);
    float ax = bfl(sv) * di * di, ay = bfh(sv) * di * di;
    int beg = rowptr[i], end = rowptr[i + 1];
    for (int p = beg; p < end; p += 16) {
        int s[16]; float n[16]; unsigned int r[16];
#pragma unroll
        for (int j = 0; j < 16; j++) {
            int q = p + j;
            s[j] = csr_src[q < end ? q : end - 1];
        }
#pragma unroll
        for (int j = 0; j < 16; j++) n[j] = dinv[s[j]];
#pragma unroll
        for (int j = 0; j < 16; j++)
            r[j] = *(const unsigned int*)(h0 + (size_t)s[j] * 128 + c2);
#pragma unroll
        for (int j = 0; j < 16; j++) n[j] = (p + j < end) ? n[j] * di : 0.f;
#pragma unroll
        for (int j = 0; j < 16; j++) {
            ax = fmaf(bfl(r[j]), n[j], ax);
            ay = fmaf(bfh(r[j]), n[j], ay);
        }
    }
    ax += b1[c2];
    ay += b1[c2 + 1];
    ax = ax > 0.f ? ax : 0.f;
    ay = ay > 0.f ? ay : 0.f;
    unsigned int pk = ((unsigned int)f2bf(ay) << 16) | (unsigned int)f2bf(ax);
    *(unsigned int*)(hb + (size_t)i * 128 + c2) = pk;
}

// ------- fused layer 2: g = agg(hb); out = g @ WtC + bias (MFMA epilogue) ---
// agg(h@W) == agg(h)@W by linearity. Block = 256 thr / 4 waves / 16 nodes.

#define LDG 136

__global__ __launch_bounds__(256) void k_agg2g(const unsigned short* __restrict__ hb,
                                               const int* __restrict__ rowptr,
                                               const int* __restrict__ csr_src,
                                               const float* __restrict__ dinv,
                                               const unsigned short* __restrict__ WtC,
                                               const float* __restrict__ bmu,
                                               const float* __restrict__ bls,
                                               float* __restrict__ out) {
    __shared__ unsigned short g[16 * LDG];
    int t = threadIdx.x;
    int wv = t >> 6, lane = t & 63;
    int nodeBase = blockIdx.x * 16;
    int c2 = lane * 2;

#pragma unroll 1
    for (int j4 = 0; j4 < 4; j4++) {
        int i = __builtin_amdgcn_readfirstlane(nodeBase + wv * 4 + j4);
        float di = dinv[i];
        unsigned int sv = *(const unsigned int*)(hb + (size_t)i * 128 + c2);
        float ax = bfl(sv) * di * di, ay = bfh(sv) * di * di;
        int beg = rowptr[i], end = rowptr[i + 1];
        for (int p = beg; p < end; p += 16) {
            int s[16]; float n[16]; unsigned int r[16];
#pragma unroll
            for (int j = 0; j < 16; j++) {
                int q = p + j;
                s[j] = csr_src[q < end ? q : end - 1];
            }
#pragma unroll
            for (int j = 0; j < 16; j++) n[j] = dinv[s[j]];
#pragma unroll
            for (int j = 0; j < 16; j++)
                r[j] = *(const unsigned int*)(hb + (size_t)s[j] * 128 + c2);
#pragma unroll
            for (int j = 0; j < 16; j++) n[j] = (p + j < end) ? n[j] * di : 0.f;
#pragma unroll
            for (int j = 0; j < 16; j++) {
                ax = fmaf(bfl(r[j]), n[j], ax);
                ay = fmaf(bfh(r[j]), n[j], ay);
            }
        }
        unsigned int pk = ((unsigned int)f2bf(ay) << 16) | (unsigned int)f2bf(ax);
        *(unsigned int*)(g + (wv * 4 + j4) * LDG + c2) = pk;
    }
    __syncthreads();

    // MFMA: wave wv computes output cols [wv*32, wv*32+32)
    int quad = lane >> 4, lm = lane & 15;
    bf16x8 a[4];
#pragma unroll
    for (int ks = 0; ks < 4; ks++)
        a[ks] = *(const bf16x8*)(g + lm * LDG + ks * 32 + quad * 8);

#pragma unroll
    for (int nt2 = 0; nt2 < 2; nt2++) {
        int nt = wv * 2 + nt2;
        f32x4 acc = {};
        const unsigned short* Wp = WtC + (nt * 16 + lm) * 128 + quad * 8;
#pragma unroll
        for (int ks = 0; ks < 4; ks++) {
            bf16x8 b = *(const bf16x8*)(Wp + ks * 32);
            acc = __builtin_amdgcn_mfma_f32_16x16x32_bf16(a[ks], b, acc, 0, 0, 0);
        }
        int col = nt * 16 + lm;
#pragma unroll
        for (int reg = 0; reg < 4; reg++) {
            int row = nodeBase + quad * 4 + reg;
            float v = acc[reg];
            if (col < 64)
                out[(size_t)row * 64 + col] = v + bmu[col];
            else
                out[(size_t)N_NODES * 64 + (size_t)row * 64 + (col - 64)] = v + bls[col - 64];
        }
    }
}

// ---------------- launch ----------------

extern "C" void kernel_launch(void* const* d_in, const int* in_sizes, int n_in,
                              void* d_out, int out_size, void* d_ws, size_t ws_size,
                              hipStream_t stream) {
    const float* x    = (const float*)d_in[0];
    const int*   ei   = (const int*)d_in[1];
    const float* W1   = (const float*)d_in[2];
    const float* b1   = (const float*)d_in[3];
    const float* Wmu  = (const float*)d_in[4];
    const float* bmu  = (const float*)d_in[5];
    const float* Wls  = (const float*)d_in[6];
    const float* bls  = (const float*)d_in[7];
    const int* src = ei;
    const int* dst = ei + N_EDGES;

    char* p = (char*)d_ws;
    unsigned short* bufA = (unsigned short*)p; p += (size_t)N_NODES * 128 * 2; // h0 (bf16)
    unsigned short* bufH = (unsigned short*)p; p += (size_t)N_NODES * 128 * 2; // h  (bf16)
    unsigned short* Wt1  = (unsigned short*)p; p += 128 * 128 * 2;
    unsigned short* WtC  = (unsigned short*)p; p += 128 * 128 * 2;
    int*   Cm      = (int*)p;   p += (size_t)NBLK * NB * 4;
    int*   bktSum  = (int*)p;   p += 256 * 4;
    int*   bktBase = (int*)p;   p += 256 * 4;
    int*   rowptr  = (int*)p;   p += 400016;
    float* dinv    = (float*)p; p += 400000;
    unsigned int* bucketed = (unsigned int*)p; p += (size_t)N_EDGES * 4;
    int*   csr_src = (int*)p;   p += (size_t)N_EDGES * 4;

    // CSR build
    k_phaseA<<<NBLK, 256, 0, stream>>>(dst, Cm);
    k_scanBkt<<<NB, 256, 0, stream>>>(Cm, bktSum);
    k_scanBase<<<1, 256, 0, stream>>>(bktSum, bktBase);
    k_phaseB<<<NBLK, 256, 0, stream>>>(src, dst, Cm, bktBase, bucketed);
    k_phaseC<<<NB, 512, 0, stream>>>(bucketed, bktBase, rowptr, dinv, csr_src);

    k_prepW<<<64, 256, 0, stream>>>(W1, Wmu, Wls, Wt1, WtC);

    int gblk = (N_NODES + 127) / 128;   // 782

    // layer 1: h0 = x @ W1 (MFMA) ; h = relu(agg(h0) + b1) (bf16 out)
    k_gemm1<<<gblk, 256, 0, stream>>>(x, Wt1, bufA);
    k_agg1<<<N_NODES / 4, 256, 0, stream>>>(bufA, rowptr, csr_src, dinv, b1, bufH);

    // layer 2 (reordered): out = agg(h) @ [Wmu|Wls] + bias, fused
    k_agg2g<<<N_NODES / 16, 256, 0, stream>>>(bufH, rowptr, csr_src, dinv,
                                              WtC, bmu, bls, (float*)d_out);
}